// Round 16
// baseline (359.888 us; speedup 1.0000x reference)
//
#include <hip/hip_runtime.h>
#include <hip/hip_fp16.h>

#define ND 56
#define HD 64
#define ESUM_MAX 512
#define XROW 72      // xh row stride in f16
#define CHUNK 96     // force queue entries per phase (12 teams x 8 rows)

typedef float v4f __attribute__((ext_vector_type(4)));
typedef _Float16 v4h __attribute__((ext_vector_type(4)));
typedef _Float16 half8 __attribute__((ext_vector_type(8)));
typedef float f32x4 __attribute__((ext_vector_type(4)));

__device__ __forceinline__ unsigned pk2h(float a, float b) {
    unsigned short ha = __builtin_bit_cast(unsigned short, (_Float16)a);
    unsigned short hb = __builtin_bit_cast(unsigned short, (_Float16)b);
    return (unsigned)ha | ((unsigned)hb << 16);
}

__global__ __launch_bounds__(256) void zero_kernel(float* __restrict__ p, int n) {
    int i = blockIdx.x * 256 + threadIdx.x;
    if (i < n) p[i] = 0.f;
}

// MFMA MLP fwd+bwd (round-15 exact; one wave = 16 atoms, weights in reg B-frags).
__global__ __launch_bounds__(256, 2) void mlp_kernel(
    const float* __restrict__ x, const int* __restrict__ indices,
    const float* __restrict__ W1, const float* __restrict__ b1,
    const float* __restrict__ W2, const float* __restrict__ b2,
    const float* __restrict__ W3, const float* __restrict__ b3,
    float* __restrict__ e_out, _Float16* __restrict__ dEdD,
    int natoms, int nconf)
{
    __shared__ _Float16 wfrag[4][4096];
    __shared__ _Float16 xh[4][16 * XROW];
    __shared__ float esum[ESUM_MAX];

    const int tid = threadIdx.x;
    for (int idx = tid; idx < 4 * 4096; idx += 256) {
        const int mat = idx >> 12;
        const int r   = idx & 4095;
        const int j  = r & 7;
        const int ln = (r >> 3) & 63;
        const int nt = (r >> 9) & 3;
        const int ks = r >> 11;
        const int k = ks * 32 + (ln >> 4) * 8 + j;
        const int n = nt * 16 + (ln & 15);
        float v;
        if (mat == 0)      v = (k < ND) ? W1[k * HD + n] : 0.f;
        else if (mat == 1) v = W2[k * HD + n];
        else if (mat == 2) v = W2[n * HD + k];
        else               v = (n < ND) ? W1[n * HD + k] : 0.f;
        wfrag[mat][r] = (_Float16)v;
    }
    for (int i = tid; i < ESUM_MAX; i += 256) esum[i] = 0.f;
    __syncthreads();

    const int w = tid >> 6, lane = tid & 63;
    const int col = lane & 15, g = lane >> 4;

    half8 wb[4][2][4];
    #pragma unroll
    for (int mat = 0; mat < 4; ++mat)
        #pragma unroll
        for (int ks = 0; ks < 2; ++ks)
            #pragma unroll
            for (int t = 0; t < 4; ++t)
                wb[mat][ks][t] = *reinterpret_cast<const half8*>(
                    &wfrag[mat][((ks * 4 + t) * 64 + lane) * 8]);

    float b1v[4], b2v[4], w3v[4];
    #pragma unroll
    for (int t = 0; t < 4; ++t) {
        b1v[t] = b1[t * 16 + col];
        b2v[t] = b2[t * 16 + col];
        w3v[t] = W3[t * 16 + col];
    }
    const float b3v = b3[0];
    const bool ldsE = (nconf <= ESUM_MAX);

    _Float16* xw = &xh[w][0];
    const int nGroups = (natoms + 15) >> 4;

    for (int grp = blockIdx.x * 4 + w; grp < nGroups; grp += gridDim.x * 4) {
        const int abase = grp * 16;

        #pragma unroll
        for (int c = 0; c < 4; ++c) {
            const int v = lane * 4 + c * 256;
            const int atom = v >> 6, d = v & 63;
            unsigned long long u = 0ull;
            if (d < ND && abase + atom < natoms) {
                const v4f xv = *reinterpret_cast<const v4f*>(
                    &x[(size_t)(abase + atom) * ND + d]);
                u = (unsigned long long)pk2h(xv.x, xv.y)
                  | ((unsigned long long)pk2h(xv.z, xv.w) << 32);
            }
            *reinterpret_cast<unsigned long long*>(&xw[atom * XROW + d]) = u;
        }

        f32x4 z1[4];
        #pragma unroll
        for (int t = 0; t < 4; ++t) z1[t] = f32x4{b1v[t], b1v[t], b1v[t], b1v[t]};
        #pragma unroll
        for (int ks = 0; ks < 2; ++ks) {
            const half8 a = *reinterpret_cast<const half8*>(
                &xw[col * XROW + g * 8 + ks * 32]);
            #pragma unroll
            for (int t = 0; t < 4; ++t)
                z1[t] = __builtin_amdgcn_mfma_f32_16x16x32_f16(a, wb[0][ks][t], z1[t], 0, 0, 0);
        }
        #pragma unroll
        for (int t = 0; t < 4; ++t)
            #pragma unroll
            for (int i = 0; i < 4; ++i) {
                const float z = z1[t][i];
                const float h = z / (1.f + __expf(-z));
                const float hn = __shfl_xor(h, 1);
                if ((lane & 1) == 0)
                    *reinterpret_cast<unsigned*>(
                        &xw[(4 * g + i) * XROW + t * 16 + col]) = pk2h(h, hn);
            }

        f32x4 z2[4];
        #pragma unroll
        for (int t = 0; t < 4; ++t) z2[t] = f32x4{b2v[t], b2v[t], b2v[t], b2v[t]};
        #pragma unroll
        for (int ks = 0; ks < 2; ++ks) {
            const half8 a = *reinterpret_cast<const half8*>(
                &xw[col * XROW + g * 8 + ks * 32]);
            #pragma unroll
            for (int t = 0; t < 4; ++t)
                z2[t] = __builtin_amdgcn_mfma_f32_16x16x32_f16(a, wb[1][ks][t], z2[t], 0, 0, 0);
        }
        float e0 = 0.f, e1 = 0.f, e2 = 0.f, e3 = 0.f;
        #pragma unroll
        for (int t = 0; t < 4; ++t)
            #pragma unroll
            for (int i = 0; i < 4; ++i) {
                const float z = z2[t][i];
                const float s = 1.f / (1.f + __expf(-z));
                const float h2 = z * s;
                const float ec = h2 * w3v[t];
                if (i == 0) e0 += ec; else if (i == 1) e1 += ec;
                else if (i == 2) e2 += ec; else e3 += ec;
                const float gv = w3v[t] * (s * (1.f + z * (1.f - s)));
                const float gn = __shfl_xor(gv, 1);
                if ((lane & 1) == 0)
                    *reinterpret_cast<unsigned*>(
                        &xw[(4 * g + i) * XROW + t * 16 + col]) = pk2h(gv, gn);
            }
        float e[4] = {e0, e1, e2, e3};
        #pragma unroll
        for (int i = 0; i < 4; ++i) {
            e[i] += __shfl_xor(e[i], 1);
            e[i] += __shfl_xor(e[i], 2);
            e[i] += __shfl_xor(e[i], 4);
            e[i] += __shfl_xor(e[i], 8);
        }
        if (col == 0) {
            #pragma unroll
            for (int i = 0; i < 4; ++i) {
                const int atom = abase + 4 * g + i;
                if (atom < natoms) {
                    const int conf = indices[atom];
                    if (ldsE) atomicAdd(&esum[conf], e[i] + b3v);
                    else      unsafeAtomicAdd(&e_out[conf], e[i] + b3v);
                }
            }
        }

        f32x4 dh[4];
        #pragma unroll
        for (int t = 0; t < 4; ++t) dh[t] = f32x4{0.f, 0.f, 0.f, 0.f};
        #pragma unroll
        for (int ks = 0; ks < 2; ++ks) {
            const half8 a = *reinterpret_cast<const half8*>(
                &xw[col * XROW + g * 8 + ks * 32]);
            #pragma unroll
            for (int t = 0; t < 4; ++t)
                dh[t] = __builtin_amdgcn_mfma_f32_16x16x32_f16(a, wb[2][ks][t], dh[t], 0, 0, 0);
        }
        #pragma unroll
        for (int t = 0; t < 4; ++t)
            #pragma unroll
            for (int i = 0; i < 4; ++i) {
                const float z = z1[t][i];
                const float s = 1.f / (1.f + __expf(-z));
                const float gv = dh[t][i] * (s * (1.f + z * (1.f - s)));
                const float gn = __shfl_xor(gv, 1);
                if ((lane & 1) == 0)
                    *reinterpret_cast<unsigned*>(
                        &xw[(4 * g + i) * XROW + t * 16 + col]) = pk2h(gv, gn);
            }

        f32x4 dx[4];
        #pragma unroll
        for (int t = 0; t < 4; ++t) dx[t] = f32x4{0.f, 0.f, 0.f, 0.f};
        #pragma unroll
        for (int ks = 0; ks < 2; ++ks) {
            const half8 a = *reinterpret_cast<const half8*>(
                &xw[col * XROW + g * 8 + ks * 32]);
            #pragma unroll
            for (int t = 0; t < 4; ++t)
                dx[t] = __builtin_amdgcn_mfma_f32_16x16x32_f16(a, wb[3][ks][t], dx[t], 0, 0, 0);
        }
        #pragma unroll
        for (int t = 0; t < 4; ++t)
            #pragma unroll
            for (int i = 0; i < 4; ++i) {
                const float v = dx[t][i];
                const float vn = __shfl_xor(v, 1);
                if ((lane & 1) == 0)
                    *reinterpret_cast<unsigned*>(
                        &xw[(4 * g + i) * XROW + t * 16 + col]) = pk2h(v, vn);
            }
        #pragma unroll
        for (int c = 0; c < 2; ++c) {
            const int atom = lane >> 2;
            const int seg = (lane & 3) * 2 + c;
            const half8 vv = *reinterpret_cast<const half8*>(&xw[atom * XROW + seg * 8]);
            if (abase + atom < natoms)
                *reinterpret_cast<half8*>(
                    &dEdD[(size_t)(abase + atom) * 64 + seg * 8]) = vv;
        }
    }

    __syncthreads();
    if (ldsE) {
        for (int c = tid; c < nconf; c += 256) {
            const float v = esum[c];
            if (v != 0.f) unsafeAtomicAdd(&e_out[c], v);
        }
    }
}

// ---- force: producer/consumer wave specialization ------------------------
// Waves 0-2 (12 x 16-lane teams) stream xd + gather dEdD, push (target,val)
// into a double-buffered LDS queue. Wave 3 issues ALL global atomics, so
// producer waves' vmcnt streams contain only loads (no atomic retirement
// stalls), and the atomic drain overlaps the stream instead of following it.
__global__ __launch_bounds__(256) void force_kernel(
    const float* __restrict__ xd,       // [M*ND]
    const int*   __restrict__ xd_indx,  // [M*3]
    const int*   __restrict__ unique_j, // [M]
    const _Float16* __restrict__ dEdD,  // [natoms*64] halfs
    float* __restrict__ out_f,          // [3*natoms] (pre-zeroed d_out region)
    int M, int CH)
{
    __shared__ int   qi[2][CHUNK];
    __shared__ float qv[2][CHUNK];

    const int b = blockIdx.x, tid = threadIdx.x;
    const int mstart = b * CH;
    const int mend   = min(mstart + CH, M);
    if (mstart >= M) return;               // uniform per block

    const int wave = tid >> 6;
    const int nChunks = CH / CHUNK;        // CH is a multiple of CHUNK

    if (wave < 3) {
        const int team = tid >> 4;         // 0..11
        const int sub  = tid & 15;
        for (int c = 0; c < nChunks; ++c) {
            const int base = mstart + c * CHUNK + team * 8;
            #pragma unroll
            for (int r = 0; r < 8; ++r) {
                const int m = base + r;
                const bool act = (m < mend);
                float p = 0.f;
                int tgt = -1;
                if (act && sub < 14) {
                    const int a = __builtin_nontemporal_load(xd_indx + 3 * (size_t)m);
                    const v4f u = __builtin_nontemporal_load(
                        reinterpret_cast<const v4f*>(xd) + (size_t)m * 14 + sub);
                    const v4h hv = reinterpret_cast<const v4h*>(dEdD + ((size_t)a << 6))[sub];
                    p = fmaf(u.x, (float)hv.x,
                        fmaf(u.y, (float)hv.y,
                        fmaf(u.z, (float)hv.z, u.w * (float)hv.w)));
                }
                p += __shfl_xor(p, 1);
                p += __shfl_xor(p, 2);
                p += __shfl_xor(p, 4);
                p += __shfl_xor(p, 8);
                if (act && sub == 0) {
                    const int coord = __builtin_nontemporal_load(xd_indx + 3 * (size_t)m + 2);
                    const int j     = __builtin_nontemporal_load(unique_j + m);
                    tgt = j * 3 + coord;
                }
                if (sub == 0) {
                    qi[c & 1][team * 8 + r] = tgt;
                    qv[c & 1][team * 8 + r] = p;
                }
            }
            __syncthreads();               // publish chunk c / retire c-1
        }
        __syncthreads();                   // final phase: consumer drains last
    } else {
        const int lane = tid & 63;
        __syncthreads();                   // wait for chunk 0  (c=0 barrier)
        for (int c = 1; c <= nChunks; ++c) {
            const int buf = (c - 1) & 1;
            #pragma unroll
            for (int i = 0; i < 2; ++i) {
                const int s = lane + i * 64;
                if (s < CHUNK) {
                    const int t = qi[buf][s];
                    if (t >= 0) unsafeAtomicAdd(&out_f[t], qv[buf][s]);
                }
            }
            if (c < nChunks) __syncthreads();
        }
    }
}

extern "C" void kernel_launch(void* const* d_in, const int* in_sizes, int n_in,
                              void* d_out, int out_size, void* d_ws, size_t ws_size,
                              hipStream_t stream) {
    const float* x        = (const float*)d_in[0];
    const float* xd       = (const float*)d_in[1];
    const int*   indices  = (const int*)d_in[2];
    const int*   xd_indx  = (const int*)d_in[4];
    const int*   unique_j = (const int*)d_in[5];
    const float* W1 = (const float*)d_in[6];
    const float* b1 = (const float*)d_in[7];
    const float* W2 = (const float*)d_in[8];
    const float* b2 = (const float*)d_in[9];
    const float* W3 = (const float*)d_in[10];
    const float* b3 = (const float*)d_in[11];

    const int natoms = in_sizes[0] / ND;
    const int M      = in_sizes[1] / ND;
    const int nconf  = in_sizes[3];

    float*    out_e = (float*)d_out;           // [nconf]
    float*    out_f = out_e + nconf;           // [3*natoms]
    _Float16* dEdDh = (_Float16*)d_ws;         // [natoms*64] halfs (6.4 MB)

    // d_out is poisoned once before timing; zero it every call.
    zero_kernel<<<(out_size + 255) / 256, 256, 0, stream>>>((float*)d_out, out_size);

    mlp_kernel<<<512, 256, 0, stream>>>(
        x, indices, W1, b1, W2, b2, W3, b3, out_e, dEdDh, natoms, nconf);

    // CH = multiple of CHUNK, ~M/2048
    int CH = (M + 2047) / 2048;
    CH = ((CH + CHUNK - 1) / CHUNK) * CHUNK;
    const int fGrid = (M + CH - 1) / CH;
    force_kernel<<<fGrid, 256, 0, stream>>>(
        xd, xd_indx, unique_j, dEdDh, out_f, M, CH);
}

// Round 17
// 283.946 us; speedup vs baseline: 1.2675x; 1.2675x over previous
//
#include <hip/hip_runtime.h>
#include <hip/hip_fp16.h>

#define ND 56
#define HD 64
#define ESUM_MAX 512
#define XROW 72      // xh row stride in f16
#define FBLK 2048

typedef float v4f __attribute__((ext_vector_type(4)));
typedef _Float16 v4h __attribute__((ext_vector_type(4)));
typedef _Float16 half8 __attribute__((ext_vector_type(8)));
typedef float f32x4 __attribute__((ext_vector_type(4)));

__device__ __forceinline__ unsigned pk2h(float a, float b) {
    unsigned short ha = __builtin_bit_cast(unsigned short, (_Float16)a);
    unsigned short hb = __builtin_bit_cast(unsigned short, (_Float16)b);
    return (unsigned)ha | ((unsigned)hb << 16);
}

__global__ __launch_bounds__(256) void zero_kernel(float* __restrict__ p, int n) {
    int i = blockIdx.x * 256 + threadIdx.x;
    if (i < n) p[i] = 0.f;
}

// MFMA MLP fwd+bwd (round-15 exact; one wave = 16 atoms, weights in reg B-frags).
__global__ __launch_bounds__(256, 2) void mlp_kernel(
    const float* __restrict__ x, const int* __restrict__ indices,
    const float* __restrict__ W1, const float* __restrict__ b1,
    const float* __restrict__ W2, const float* __restrict__ b2,
    const float* __restrict__ W3, const float* __restrict__ b3,
    float* __restrict__ e_out, _Float16* __restrict__ dEdD,
    int natoms, int nconf)
{
    __shared__ _Float16 wfrag[4][4096];
    __shared__ _Float16 xh[4][16 * XROW];
    __shared__ float esum[ESUM_MAX];

    const int tid = threadIdx.x;
    for (int idx = tid; idx < 4 * 4096; idx += 256) {
        const int mat = idx >> 12;
        const int r   = idx & 4095;
        const int j  = r & 7;
        const int ln = (r >> 3) & 63;
        const int nt = (r >> 9) & 3;
        const int ks = r >> 11;
        const int k = ks * 32 + (ln >> 4) * 8 + j;
        const int n = nt * 16 + (ln & 15);
        float v;
        if (mat == 0)      v = (k < ND) ? W1[k * HD + n] : 0.f;
        else if (mat == 1) v = W2[k * HD + n];
        else if (mat == 2) v = W2[n * HD + k];
        else               v = (n < ND) ? W1[n * HD + k] : 0.f;
        wfrag[mat][r] = (_Float16)v;
    }
    for (int i = tid; i < ESUM_MAX; i += 256) esum[i] = 0.f;
    __syncthreads();

    const int w = tid >> 6, lane = tid & 63;
    const int col = lane & 15, g = lane >> 4;

    half8 wb[4][2][4];
    #pragma unroll
    for (int mat = 0; mat < 4; ++mat)
        #pragma unroll
        for (int ks = 0; ks < 2; ++ks)
            #pragma unroll
            for (int t = 0; t < 4; ++t)
                wb[mat][ks][t] = *reinterpret_cast<const half8*>(
                    &wfrag[mat][((ks * 4 + t) * 64 + lane) * 8]);

    float b1v[4], b2v[4], w3v[4];
    #pragma unroll
    for (int t = 0; t < 4; ++t) {
        b1v[t] = b1[t * 16 + col];
        b2v[t] = b2[t * 16 + col];
        w3v[t] = W3[t * 16 + col];
    }
    const float b3v = b3[0];
    const bool ldsE = (nconf <= ESUM_MAX);

    _Float16* xw = &xh[w][0];
    const int nGroups = (natoms + 15) >> 4;

    for (int grp = blockIdx.x * 4 + w; grp < nGroups; grp += gridDim.x * 4) {
        const int abase = grp * 16;

        #pragma unroll
        for (int c = 0; c < 4; ++c) {
            const int v = lane * 4 + c * 256;
            const int atom = v >> 6, d = v & 63;
            unsigned long long u = 0ull;
            if (d < ND && abase + atom < natoms) {
                const v4f xv = *reinterpret_cast<const v4f*>(
                    &x[(size_t)(abase + atom) * ND + d]);
                u = (unsigned long long)pk2h(xv.x, xv.y)
                  | ((unsigned long long)pk2h(xv.z, xv.w) << 32);
            }
            *reinterpret_cast<unsigned long long*>(&xw[atom * XROW + d]) = u;
        }

        f32x4 z1[4];
        #pragma unroll
        for (int t = 0; t < 4; ++t) z1[t] = f32x4{b1v[t], b1v[t], b1v[t], b1v[t]};
        #pragma unroll
        for (int ks = 0; ks < 2; ++ks) {
            const half8 a = *reinterpret_cast<const half8*>(
                &xw[col * XROW + g * 8 + ks * 32]);
            #pragma unroll
            for (int t = 0; t < 4; ++t)
                z1[t] = __builtin_amdgcn_mfma_f32_16x16x32_f16(a, wb[0][ks][t], z1[t], 0, 0, 0);
        }
        #pragma unroll
        for (int t = 0; t < 4; ++t)
            #pragma unroll
            for (int i = 0; i < 4; ++i) {
                const float z = z1[t][i];
                const float h = z / (1.f + __expf(-z));
                const float hn = __shfl_xor(h, 1);
                if ((lane & 1) == 0)
                    *reinterpret_cast<unsigned*>(
                        &xw[(4 * g + i) * XROW + t * 16 + col]) = pk2h(h, hn);
            }

        f32x4 z2[4];
        #pragma unroll
        for (int t = 0; t < 4; ++t) z2[t] = f32x4{b2v[t], b2v[t], b2v[t], b2v[t]};
        #pragma unroll
        for (int ks = 0; ks < 2; ++ks) {
            const half8 a = *reinterpret_cast<const half8*>(
                &xw[col * XROW + g * 8 + ks * 32]);
            #pragma unroll
            for (int t = 0; t < 4; ++t)
                z2[t] = __builtin_amdgcn_mfma_f32_16x16x32_f16(a, wb[1][ks][t], z2[t], 0, 0, 0);
        }
        float e0 = 0.f, e1 = 0.f, e2 = 0.f, e3 = 0.f;
        #pragma unroll
        for (int t = 0; t < 4; ++t)
            #pragma unroll
            for (int i = 0; i < 4; ++i) {
                const float z = z2[t][i];
                const float s = 1.f / (1.f + __expf(-z));
                const float h2 = z * s;
                const float ec = h2 * w3v[t];
                if (i == 0) e0 += ec; else if (i == 1) e1 += ec;
                else if (i == 2) e2 += ec; else e3 += ec;
                const float gv = w3v[t] * (s * (1.f + z * (1.f - s)));
                const float gn = __shfl_xor(gv, 1);
                if ((lane & 1) == 0)
                    *reinterpret_cast<unsigned*>(
                        &xw[(4 * g + i) * XROW + t * 16 + col]) = pk2h(gv, gn);
            }
        float e[4] = {e0, e1, e2, e3};
        #pragma unroll
        for (int i = 0; i < 4; ++i) {
            e[i] += __shfl_xor(e[i], 1);
            e[i] += __shfl_xor(e[i], 2);
            e[i] += __shfl_xor(e[i], 4);
            e[i] += __shfl_xor(e[i], 8);
        }
        if (col == 0) {
            #pragma unroll
            for (int i = 0; i < 4; ++i) {
                const int atom = abase + 4 * g + i;
                if (atom < natoms) {
                    const int conf = indices[atom];
                    if (ldsE) atomicAdd(&esum[conf], e[i] + b3v);
                    else      unsafeAtomicAdd(&e_out[conf], e[i] + b3v);
                }
            }
        }

        f32x4 dh[4];
        #pragma unroll
        for (int t = 0; t < 4; ++t) dh[t] = f32x4{0.f, 0.f, 0.f, 0.f};
        #pragma unroll
        for (int ks = 0; ks < 2; ++ks) {
            const half8 a = *reinterpret_cast<const half8*>(
                &xw[col * XROW + g * 8 + ks * 32]);
            #pragma unroll
            for (int t = 0; t < 4; ++t)
                dh[t] = __builtin_amdgcn_mfma_f32_16x16x32_f16(a, wb[2][ks][t], dh[t], 0, 0, 0);
        }
        #pragma unroll
        for (int t = 0; t < 4; ++t)
            #pragma unroll
            for (int i = 0; i < 4; ++i) {
                const float z = z1[t][i];
                const float s = 1.f / (1.f + __expf(-z));
                const float gv = dh[t][i] * (s * (1.f + z * (1.f - s)));
                const float gn = __shfl_xor(gv, 1);
                if ((lane & 1) == 0)
                    *reinterpret_cast<unsigned*>(
                        &xw[(4 * g + i) * XROW + t * 16 + col]) = pk2h(gv, gn);
            }

        f32x4 dx[4];
        #pragma unroll
        for (int t = 0; t < 4; ++t) dx[t] = f32x4{0.f, 0.f, 0.f, 0.f};
        #pragma unroll
        for (int ks = 0; ks < 2; ++ks) {
            const half8 a = *reinterpret_cast<const half8*>(
                &xw[col * XROW + g * 8 + ks * 32]);
            #pragma unroll
            for (int t = 0; t < 4; ++t)
                dx[t] = __builtin_amdgcn_mfma_f32_16x16x32_f16(a, wb[3][ks][t], dx[t], 0, 0, 0);
        }
        #pragma unroll
        for (int t = 0; t < 4; ++t)
            #pragma unroll
            for (int i = 0; i < 4; ++i) {
                const float v = dx[t][i];
                const float vn = __shfl_xor(v, 1);
                if ((lane & 1) == 0)
                    *reinterpret_cast<unsigned*>(
                        &xw[(4 * g + i) * XROW + t * 16 + col]) = pk2h(v, vn);
            }
        #pragma unroll
        for (int c = 0; c < 2; ++c) {
            const int atom = lane >> 2;
            const int seg = (lane & 3) * 2 + c;
            const half8 vv = *reinterpret_cast<const half8*>(&xw[atom * XROW + seg * 8]);
            if (abase + atom < natoms)
                *reinterpret_cast<half8*>(
                    &dEdD[(size_t)(abase + atom) * 64 + seg * 8]) = vv;
        }
    }

    __syncthreads();
    if (ldsE) {
        for (int c = tid; c < nconf; c += 256) {
            const float v = esum[c];
            if (v != 0.f) unsafeAtomicAdd(&e_out[c], v);
        }
    }
}

// Grid-strided force kernel, 4x unrolled: 4 independent 16-row bodies per
// outer iteration. All pointers no-alias, so the scheduler hoists the 4
// bodies' loads above the 4 atomics -> one atomic-ack stall per 64 rows
// instead of per 16 (the in-order vmcnt coupling measured in r10/r12).
__global__ __launch_bounds__(256) void force_kernel(
    const float* __restrict__ xd,       // [M*ND]
    const int*   __restrict__ xd_indx,  // [M*3]
    const int*   __restrict__ unique_j, // [M]
    const _Float16* __restrict__ dEdD,  // [natoms*64] halfs
    float* __restrict__ out_f,          // [3*natoms] (pre-zeroed d_out region)
    int M, int CH)
{
    const int b = blockIdx.x, tid = threadIdx.x;
    const int team = tid >> 4, sub = tid & 15;   // 16 teams/block
    const int mstart = b * CH;
    const int mend   = min(mstart + CH, M);

    for (int m0 = mstart; m0 < mend; m0 += 64) {
        #pragma unroll
        for (int k = 0; k < 4; ++k) {
            const int m = m0 + k * 16 + team;
            float partial = 0.f;
            const bool act = (m < mend);
            if (act && sub < 14) {
                const int a = __builtin_nontemporal_load(xd_indx + 3 * (size_t)m);
                const v4f u = __builtin_nontemporal_load(
                    reinterpret_cast<const v4f*>(xd) + (size_t)m * 14 + sub);
                const v4h hv = reinterpret_cast<const v4h*>(dEdD + ((size_t)a << 6))[sub];
                partial = fmaf(u.x, (float)hv.x,
                          fmaf(u.y, (float)hv.y,
                          fmaf(u.z, (float)hv.z, u.w * (float)hv.w)));
            }
            partial += __shfl_xor(partial, 1);
            partial += __shfl_xor(partial, 2);
            partial += __shfl_xor(partial, 4);
            partial += __shfl_xor(partial, 8);

            if (act && sub == 0) {
                const int coord = __builtin_nontemporal_load(xd_indx + 3 * (size_t)m + 2);
                const int j     = __builtin_nontemporal_load(unique_j + m);
                unsafeAtomicAdd(&out_f[(size_t)j * 3 + coord], partial);
            }
        }
    }
}

extern "C" void kernel_launch(void* const* d_in, const int* in_sizes, int n_in,
                              void* d_out, int out_size, void* d_ws, size_t ws_size,
                              hipStream_t stream) {
    const float* x        = (const float*)d_in[0];
    const float* xd       = (const float*)d_in[1];
    const int*   indices  = (const int*)d_in[2];
    const int*   xd_indx  = (const int*)d_in[4];
    const int*   unique_j = (const int*)d_in[5];
    const float* W1 = (const float*)d_in[6];
    const float* b1 = (const float*)d_in[7];
    const float* W2 = (const float*)d_in[8];
    const float* b2 = (const float*)d_in[9];
    const float* W3 = (const float*)d_in[10];
    const float* b3 = (const float*)d_in[11];

    const int natoms = in_sizes[0] / ND;
    const int M      = in_sizes[1] / ND;
    const int nconf  = in_sizes[3];

    float*    out_e = (float*)d_out;           // [nconf]
    float*    out_f = out_e + nconf;           // [3*natoms]
    _Float16* dEdDh = (_Float16*)d_ws;         // [natoms*64] halfs (6.4 MB)

    // d_out is poisoned once before timing; zero it every call.
    zero_kernel<<<(out_size + 255) / 256, 256, 0, stream>>>((float*)d_out, out_size);

    mlp_kernel<<<512, 256, 0, stream>>>(
        x, indices, W1, b1, W2, b2, W3, b3, out_e, dEdDh, natoms, nconf);

    // CH = multiple of 64 (unroll step), ~M/FBLK
    int CH = (M + FBLK - 1) / FBLK;
    CH = (CH + 63) & ~63;
    const int fGrid = (M + CH - 1) / CH;
    force_kernel<<<fGrid, 256, 0, stream>>>(
        xd, xd_indx, unique_j, dEdDh, out_f, M, CH);
}

// Round 18
// 274.921 us; speedup vs baseline: 1.3091x; 1.0328x over previous
//
#include <hip/hip_runtime.h>
#include <hip/hip_fp16.h>

#define ND 56
#define HD 64
#define ESUM_MAX 512
#define XROW 72      // xh row stride in f16
#define FBLK 2048

typedef float v4f __attribute__((ext_vector_type(4)));
typedef _Float16 v4h __attribute__((ext_vector_type(4)));
typedef _Float16 half8 __attribute__((ext_vector_type(8)));
typedef float f32x4 __attribute__((ext_vector_type(4)));

__device__ __forceinline__ unsigned pk2h(float a, float b) {
    unsigned short ha = __builtin_bit_cast(unsigned short, (_Float16)a);
    unsigned short hb = __builtin_bit_cast(unsigned short, (_Float16)b);
    return (unsigned)ha | ((unsigned)hb << 16);
}

__global__ __launch_bounds__(256) void zero_kernel(float* __restrict__ p, int n) {
    int i = blockIdx.x * 256 + threadIdx.x;
    if (i < n) p[i] = 0.f;
}

// MFMA MLP fwd+bwd (round-15 exact; one wave = 16 atoms, weights in reg B-frags).
__global__ __launch_bounds__(256, 2) void mlp_kernel(
    const float* __restrict__ x, const int* __restrict__ indices,
    const float* __restrict__ W1, const float* __restrict__ b1,
    const float* __restrict__ W2, const float* __restrict__ b2,
    const float* __restrict__ W3, const float* __restrict__ b3,
    float* __restrict__ e_out, _Float16* __restrict__ dEdD,
    int natoms, int nconf)
{
    __shared__ _Float16 wfrag[4][4096];
    __shared__ _Float16 xh[4][16 * XROW];
    __shared__ float esum[ESUM_MAX];

    const int tid = threadIdx.x;
    for (int idx = tid; idx < 4 * 4096; idx += 256) {
        const int mat = idx >> 12;
        const int r   = idx & 4095;
        const int j  = r & 7;
        const int ln = (r >> 3) & 63;
        const int nt = (r >> 9) & 3;
        const int ks = r >> 11;
        const int k = ks * 32 + (ln >> 4) * 8 + j;
        const int n = nt * 16 + (ln & 15);
        float v;
        if (mat == 0)      v = (k < ND) ? W1[k * HD + n] : 0.f;
        else if (mat == 1) v = W2[k * HD + n];
        else if (mat == 2) v = W2[n * HD + k];
        else               v = (n < ND) ? W1[n * HD + k] : 0.f;
        wfrag[mat][r] = (_Float16)v;
    }
    for (int i = tid; i < ESUM_MAX; i += 256) esum[i] = 0.f;
    __syncthreads();

    const int w = tid >> 6, lane = tid & 63;
    const int col = lane & 15, g = lane >> 4;

    half8 wb[4][2][4];
    #pragma unroll
    for (int mat = 0; mat < 4; ++mat)
        #pragma unroll
        for (int ks = 0; ks < 2; ++ks)
            #pragma unroll
            for (int t = 0; t < 4; ++t)
                wb[mat][ks][t] = *reinterpret_cast<const half8*>(
                    &wfrag[mat][((ks * 4 + t) * 64 + lane) * 8]);

    float b1v[4], b2v[4], w3v[4];
    #pragma unroll
    for (int t = 0; t < 4; ++t) {
        b1v[t] = b1[t * 16 + col];
        b2v[t] = b2[t * 16 + col];
        w3v[t] = W3[t * 16 + col];
    }
    const float b3v = b3[0];
    const bool ldsE = (nconf <= ESUM_MAX);

    _Float16* xw = &xh[w][0];
    const int nGroups = (natoms + 15) >> 4;

    for (int grp = blockIdx.x * 4 + w; grp < nGroups; grp += gridDim.x * 4) {
        const int abase = grp * 16;

        #pragma unroll
        for (int c = 0; c < 4; ++c) {
            const int v = lane * 4 + c * 256;
            const int atom = v >> 6, d = v & 63;
            unsigned long long u = 0ull;
            if (d < ND && abase + atom < natoms) {
                const v4f xv = *reinterpret_cast<const v4f*>(
                    &x[(size_t)(abase + atom) * ND + d]);
                u = (unsigned long long)pk2h(xv.x, xv.y)
                  | ((unsigned long long)pk2h(xv.z, xv.w) << 32);
            }
            *reinterpret_cast<unsigned long long*>(&xw[atom * XROW + d]) = u;
        }

        f32x4 z1[4];
        #pragma unroll
        for (int t = 0; t < 4; ++t) z1[t] = f32x4{b1v[t], b1v[t], b1v[t], b1v[t]};
        #pragma unroll
        for (int ks = 0; ks < 2; ++ks) {
            const half8 a = *reinterpret_cast<const half8*>(
                &xw[col * XROW + g * 8 + ks * 32]);
            #pragma unroll
            for (int t = 0; t < 4; ++t)
                z1[t] = __builtin_amdgcn_mfma_f32_16x16x32_f16(a, wb[0][ks][t], z1[t], 0, 0, 0);
        }
        #pragma unroll
        for (int t = 0; t < 4; ++t)
            #pragma unroll
            for (int i = 0; i < 4; ++i) {
                const float z = z1[t][i];
                const float h = z / (1.f + __expf(-z));
                const float hn = __shfl_xor(h, 1);
                if ((lane & 1) == 0)
                    *reinterpret_cast<unsigned*>(
                        &xw[(4 * g + i) * XROW + t * 16 + col]) = pk2h(h, hn);
            }

        f32x4 z2[4];
        #pragma unroll
        for (int t = 0; t < 4; ++t) z2[t] = f32x4{b2v[t], b2v[t], b2v[t], b2v[t]};
        #pragma unroll
        for (int ks = 0; ks < 2; ++ks) {
            const half8 a = *reinterpret_cast<const half8*>(
                &xw[col * XROW + g * 8 + ks * 32]);
            #pragma unroll
            for (int t = 0; t < 4; ++t)
                z2[t] = __builtin_amdgcn_mfma_f32_16x16x32_f16(a, wb[1][ks][t], z2[t], 0, 0, 0);
        }
        float e0 = 0.f, e1 = 0.f, e2 = 0.f, e3 = 0.f;
        #pragma unroll
        for (int t = 0; t < 4; ++t)
            #pragma unroll
            for (int i = 0; i < 4; ++i) {
                const float z = z2[t][i];
                const float s = 1.f / (1.f + __expf(-z));
                const float h2 = z * s;
                const float ec = h2 * w3v[t];
                if (i == 0) e0 += ec; else if (i == 1) e1 += ec;
                else if (i == 2) e2 += ec; else e3 += ec;
                const float gv = w3v[t] * (s * (1.f + z * (1.f - s)));
                const float gn = __shfl_xor(gv, 1);
                if ((lane & 1) == 0)
                    *reinterpret_cast<unsigned*>(
                        &xw[(4 * g + i) * XROW + t * 16 + col]) = pk2h(gv, gn);
            }
        float e[4] = {e0, e1, e2, e3};
        #pragma unroll
        for (int i = 0; i < 4; ++i) {
            e[i] += __shfl_xor(e[i], 1);
            e[i] += __shfl_xor(e[i], 2);
            e[i] += __shfl_xor(e[i], 4);
            e[i] += __shfl_xor(e[i], 8);
        }
        if (col == 0) {
            #pragma unroll
            for (int i = 0; i < 4; ++i) {
                const int atom = abase + 4 * g + i;
                if (atom < natoms) {
                    const int conf = indices[atom];
                    if (ldsE) atomicAdd(&esum[conf], e[i] + b3v);
                    else      unsafeAtomicAdd(&e_out[conf], e[i] + b3v);
                }
            }
        }

        f32x4 dh[4];
        #pragma unroll
        for (int t = 0; t < 4; ++t) dh[t] = f32x4{0.f, 0.f, 0.f, 0.f};
        #pragma unroll
        for (int ks = 0; ks < 2; ++ks) {
            const half8 a = *reinterpret_cast<const half8*>(
                &xw[col * XROW + g * 8 + ks * 32]);
            #pragma unroll
            for (int t = 0; t < 4; ++t)
                dh[t] = __builtin_amdgcn_mfma_f32_16x16x32_f16(a, wb[2][ks][t], dh[t], 0, 0, 0);
        }
        #pragma unroll
        for (int t = 0; t < 4; ++t)
            #pragma unroll
            for (int i = 0; i < 4; ++i) {
                const float z = z1[t][i];
                const float s = 1.f / (1.f + __expf(-z));
                const float gv = dh[t][i] * (s * (1.f + z * (1.f - s)));
                const float gn = __shfl_xor(gv, 1);
                if ((lane & 1) == 0)
                    *reinterpret_cast<unsigned*>(
                        &xw[(4 * g + i) * XROW + t * 16 + col]) = pk2h(gv, gn);
            }

        f32x4 dx[4];
        #pragma unroll
        for (int t = 0; t < 4; ++t) dx[t] = f32x4{0.f, 0.f, 0.f, 0.f};
        #pragma unroll
        for (int ks = 0; ks < 2; ++ks) {
            const half8 a = *reinterpret_cast<const half8*>(
                &xw[col * XROW + g * 8 + ks * 32]);
            #pragma unroll
            for (int t = 0; t < 4; ++t)
                dx[t] = __builtin_amdgcn_mfma_f32_16x16x32_f16(a, wb[3][ks][t], dx[t], 0, 0, 0);
        }
        #pragma unroll
        for (int t = 0; t < 4; ++t)
            #pragma unroll
            for (int i = 0; i < 4; ++i) {
                const float v = dx[t][i];
                const float vn = __shfl_xor(v, 1);
                if ((lane & 1) == 0)
                    *reinterpret_cast<unsigned*>(
                        &xw[(4 * g + i) * XROW + t * 16 + col]) = pk2h(v, vn);
            }
        #pragma unroll
        for (int c = 0; c < 2; ++c) {
            const int atom = lane >> 2;
            const int seg = (lane & 3) * 2 + c;
            const half8 vv = *reinterpret_cast<const half8*>(&xw[atom * XROW + seg * 8]);
            if (abase + atom < natoms)
                *reinterpret_cast<half8*>(
                    &dEdD[(size_t)(abase + atom) * 64 + seg * 8]) = vv;
        }
    }

    __syncthreads();
    if (ldsE) {
        for (int c = tid; c < nconf; c += 256) {
            const float v = esum[c];
            if (v != 0.f) unsafeAtomicAdd(&e_out[c], v);
        }
    }
}

// Grid-strided force kernel (round-12 exact form: best measured config).
__global__ __launch_bounds__(256) void force_kernel(
    const float* __restrict__ xd,       // [M*ND]
    const int*   __restrict__ xd_indx,  // [M*3]
    const int*   __restrict__ unique_j, // [M]
    const _Float16* __restrict__ dEdD,  // [natoms*64] halfs
    float* __restrict__ out_f,          // [3*natoms] (pre-zeroed d_out region)
    int M, int CH)
{
    const int b = blockIdx.x, tid = threadIdx.x;
    const int team = tid >> 4, sub = tid & 15;   // 16 teams/block
    const int mstart = b * CH;
    const int mend   = min(mstart + CH, M);

    for (int m0 = mstart; m0 < mend; m0 += 16) {
        const int m = m0 + team;
        float partial = 0.f;
        const bool act = (m < mend);
        if (act && sub < 14) {
            const int a = __builtin_nontemporal_load(xd_indx + 3 * (size_t)m);
            const v4f u = __builtin_nontemporal_load(
                reinterpret_cast<const v4f*>(xd) + (size_t)m * 14 + sub);
            const v4h hv = reinterpret_cast<const v4h*>(dEdD + ((size_t)a << 6))[sub];
            partial = fmaf(u.x, (float)hv.x,
                      fmaf(u.y, (float)hv.y,
                      fmaf(u.z, (float)hv.z, u.w * (float)hv.w)));
        }
        partial += __shfl_xor(partial, 1);
        partial += __shfl_xor(partial, 2);
        partial += __shfl_xor(partial, 4);
        partial += __shfl_xor(partial, 8);

        if (act && sub == 0) {
            const int coord = __builtin_nontemporal_load(xd_indx + 3 * (size_t)m + 2);
            const int j     = __builtin_nontemporal_load(unique_j + m);
            unsafeAtomicAdd(&out_f[(size_t)j * 3 + coord], partial);
        }
    }
}

extern "C" void kernel_launch(void* const* d_in, const int* in_sizes, int n_in,
                              void* d_out, int out_size, void* d_ws, size_t ws_size,
                              hipStream_t stream) {
    const float* x        = (const float*)d_in[0];
    const float* xd       = (const float*)d_in[1];
    const int*   indices  = (const int*)d_in[2];
    const int*   xd_indx  = (const int*)d_in[4];
    const int*   unique_j = (const int*)d_in[5];
    const float* W1 = (const float*)d_in[6];
    const float* b1 = (const float*)d_in[7];
    const float* W2 = (const float*)d_in[8];
    const float* b2 = (const float*)d_in[9];
    const float* W3 = (const float*)d_in[10];
    const float* b3 = (const float*)d_in[11];

    const int natoms = in_sizes[0] / ND;
    const int M      = in_sizes[1] / ND;
    const int nconf  = in_sizes[3];

    float*    out_e = (float*)d_out;           // [nconf]
    float*    out_f = out_e + nconf;           // [3*natoms]
    _Float16* dEdDh = (_Float16*)d_ws;         // [natoms*64] halfs (6.4 MB)

    // d_out is poisoned once before timing; zero it every call.
    zero_kernel<<<(out_size + 255) / 256, 256, 0, stream>>>((float*)d_out, out_size);

    mlp_kernel<<<512, 256, 0, stream>>>(
        x, indices, W1, b1, W2, b2, W3, b3, out_e, dEdDh, natoms, nconf);

    const int CH = (M + FBLK - 1) / FBLK;
    force_kernel<<<FBLK, 256, 0, stream>>>(
        xd, xd_indx, unique_j, dEdDh, out_f, M, CH);
}